// Round 1
// baseline (183.897 us; speedup 1.0000x reference)
//
#include <hip/hip_runtime.h>
#include <hip/hip_bf16.h>

#define LATENT 256
#define CODED  64
#define NCODE  2048
#define NBATCH 64
#define HW     1024
#define NPIX   (NBATCH*HW)   // 65536

typedef __attribute__((ext_vector_type(8))) short  short8_t;   // bf16x8 MFMA frag
typedef __attribute__((ext_vector_type(4))) float  floatx4;
typedef __attribute__((ext_vector_type(4))) unsigned int uintx4;

__device__ __forceinline__ unsigned short f2bf(float f){
    unsigned int x = __builtin_bit_cast(unsigned int, f);
    unsigned int r = (x + 0x7FFFu + ((x >> 16) & 1u)) >> 16;   // RNE
    return (unsigned short)r;
}
__device__ __forceinline__ float bf2f(unsigned short u){
    unsigned int x = ((unsigned int)u) << 16;
    return __builtin_bit_cast(float, x);
}

// K0a: codebook -> bf16, cbias[j] = -0.5*||cb_j||^2.  grid 512 x 256
__global__ void k_cbprep(const float* __restrict__ cb, unsigned short* __restrict__ cbb,
                         float* __restrict__ cbias){
    int wave = threadIdx.x >> 6, lane = threadIdx.x & 63;
    int j = blockIdx.x*4 + wave;
    float v = cb[j*CODED + lane];
    cbb[j*CODED + lane] = f2bf(v);
    float s = v*v;
    #pragma unroll
    for (int o = 32; o; o >>= 1) s += __shfl_down(s, o);
    if (lane == 0) cbias[j] = -0.5f*s;
}

// K0b: W_in [64][256] -> Wt [256][64].  grid 64 x 256
__global__ void k_wt(const float* __restrict__ W_in, float* __restrict__ Wt){
    int c = threadIdx.x, d = blockIdx.x;
    Wt[c*CODED + d] = W_in[d*LATENT + c];
}

// K0c: pcb[j][n] = sum_d cb[j][d]*W_out[n][d] + b_out[n].  grid 256 x 256 (8 j per block)
__global__ void k_projcb(const float* __restrict__ cb, const float* __restrict__ W_out,
                         const float* __restrict__ b_out, float* __restrict__ pcb){
    __shared__ float cbl[8*CODED];
    int tid = threadIdx.x;
    int j0  = blockIdx.x*8;
    for (int k = tid; k < 8*CODED; k += 256) cbl[k] = cb[j0*CODED + k];
    __syncthreads();
    float wrow[CODED];
    #pragma unroll
    for (int k = 0; k < 16; k++)
        ((floatx4*)wrow)[k] = ((const floatx4*)(W_out + tid*CODED))[k];
    float bo = b_out[tid];
    for (int jj = 0; jj < 8; jj++){
        float acc = bo;
        #pragma unroll
        for (int d = 0; d < CODED; d++) acc += cbl[jj*CODED + d]*wrow[d];
        pcb[(j0+jj)*LATENT + tid] = acc;
    }
}

// K1: project_in.  zp[p][d] = sum_c z[b,c,p]*Wt[c][d] + b_in[d], stored bf16 pixel-major [p][64].
// grid 256 x 256: block = (b, 256 pixels); wave w owns d-group w*16; thread: 4 pixels x 16 d.
__global__ __launch_bounds__(256) void k_projin(
        const float* __restrict__ z, const float* __restrict__ Wt,
        const float* __restrict__ b_in, unsigned short* __restrict__ zpbf){
    __shared__ float wt[LATENT*CODED];    // 64 KB
    int tid = threadIdx.x;
    #pragma unroll
    for (int k = 0; k < 16; k++)
        ((floatx4*)wt)[k*256 + tid] = ((const floatx4*)Wt)[k*256 + tid];
    __syncthreads();
    int wave = tid >> 6, lane = tid & 63;
    int b = blockIdx.x >> 2, pbase = (blockIdx.x & 3)*256;
    int d0 = wave*16;
    const float* zb = z + (size_t)b*(LATENT*HW) + pbase + lane*4;
    floatx4 acc[4][4];
    floatx4 bi[4];
    #pragma unroll
    for (int q = 0; q < 4; q++) bi[q] = *(const floatx4*)(b_in + d0 + q*4);
    #pragma unroll
    for (int px = 0; px < 4; px++)
        #pragma unroll
        for (int q = 0; q < 4; q++) acc[px][q] = bi[q];
    #pragma unroll 4
    for (int c = 0; c < LATENT; c++){
        floatx4 zv = *(const floatx4*)(zb + c*HW);
        const floatx4* wr = (const floatx4*)(wt + c*CODED + d0);
        floatx4 w0 = wr[0], w1 = wr[1], w2 = wr[2], w3 = wr[3];
        #pragma unroll
        for (int px = 0; px < 4; px++){
            acc[px][0] += zv[px]*w0;
            acc[px][1] += zv[px]*w1;
            acc[px][2] += zv[px]*w2;
            acc[px][3] += zv[px]*w3;
        }
    }
    #pragma unroll
    for (int px = 0; px < 4; px++){
        int pg = b*HW + pbase + lane*4 + px;
        unsigned int w[8];
        #pragma unroll
        for (int q = 0; q < 4; q++){
            w[q*2+0] = (unsigned)f2bf(acc[px][q][0]) | ((unsigned)f2bf(acc[px][q][1]) << 16);
            w[q*2+1] = (unsigned)f2bf(acc[px][q][2]) | ((unsigned)f2bf(acc[px][q][3]) << 16);
        }
        uintx4 v0 = {w[0], w[1], w[2], w[3]};
        uintx4 v1 = {w[4], w[5], w[6], w[7]};
        *(uintx4*)(zpbf + (size_t)pg*CODED + d0)     = v0;
        *(uintx4*)(zpbf + (size_t)pg*CODED + d0 + 8) = v1;
    }
}

// K2: scores^T[j][p] = cb[j]·zp[p] via MFMA (A=cb rows, B=zp cols), running argmax over j.
// grid 256 x 256: wave owns 64 pixels (4 p-tiles of 16), loops 128 j-tiles.
__global__ __launch_bounds__(256) void k_argmin(
        const unsigned short* __restrict__ zpbf, const unsigned short* __restrict__ cbb,
        const float* __restrict__ cbias, int* __restrict__ idxb){
    int tid = threadIdx.x, wave = tid >> 6, lane = tid & 63;
    int col = lane & 15, g = lane >> 4;
    int pixw = blockIdx.x*256 + wave*64;
    short8_t bfr[4][2];
    #pragma unroll
    for (int i = 0; i < 4; i++)
        #pragma unroll
        for (int kg = 0; kg < 2; kg++)
            bfr[i][kg] = *(const short8_t*)(zpbf + (size_t)(pixw + i*16 + col)*CODED + kg*32 + g*8);
    float best[4]; int bidx[4];
    #pragma unroll
    for (int i = 0; i < 4; i++){ best[i] = -3.4e38f; bidx[i] = 0; }
    #pragma unroll 2
    for (int jt = 0; jt < 128; jt++){
        const unsigned short* arow = cbb + (size_t)(jt*16 + col)*CODED + g*8;
        short8_t a0 = *(const short8_t*)(arow);
        short8_t a1 = *(const short8_t*)(arow + 32);
        floatx4 bias = *(const floatx4*)(cbias + jt*16 + g*4);
        #pragma unroll
        for (int i = 0; i < 4; i++){
            floatx4 dacc = {0.f, 0.f, 0.f, 0.f};
            dacc = __builtin_amdgcn_mfma_f32_16x16x32_bf16(a0, bfr[i][0], dacc, 0, 0, 0);
            dacc = __builtin_amdgcn_mfma_f32_16x16x32_bf16(a1, bfr[i][1], dacc, 0, 0, 0);
            #pragma unroll
            for (int r = 0; r < 4; r++){
                float s = dacc[r] + bias[r];
                if (s > best[i]) { best[i] = s; bidx[i] = jt*16 + g*4 + r; }
            }
        }
    }
    #pragma unroll
    for (int i = 0; i < 4; i++){
        for (int off = 16; off < 64; off <<= 1){
            float ov = __shfl_xor(best[i], off);
            int   oi = __shfl_xor(bidx[i], off);
            if (ov > best[i] || (ov == best[i] && oi < bidx[i])) { best[i] = ov; bidx[i] = oi; }
        }
    }
    if (lane < 16){
        #pragma unroll
        for (int i = 0; i < 4; i++) idxb[pixw + i*16 + lane] = bidx[i];
    }
}

// K3: out[b][n][p] = pcb[idx[b,p]][n], via LDS transpose. grid 2048 x 256 (32 pixels/block).
__global__ void k_out(const int* __restrict__ idxb, const float* __restrict__ pcb,
                      float* __restrict__ outp){
    __shared__ float lds[32][LATENT + 1];
    int tid = threadIdx.x;
    int b = blockIdx.x >> 5, pb = (blockIdx.x & 31)*32;
    for (int k = 0; k < 32; k++){
        int j = idxb[b*HW + pb + k];
        lds[k][tid] = pcb[(size_t)j*LATENT + tid];
    }
    __syncthreads();
    int p = tid & 31, ng = tid >> 5;     // 8 n-groups of 32
    for (int k = 0; k < 32; k++){
        int n = ng*32 + k;
        outp[((size_t)b*LATENT + n)*HW + pb + p] = lds[p][n];
    }
}

// K4: loss = 1.25 * mean((zq - zp)^2).  grid 2048 x 256 (32 pixels/block, 8 threads/pixel).
__global__ void k_loss(const unsigned short* __restrict__ zpbf,
                       const unsigned short* __restrict__ cbb,
                       const int* __restrict__ idxb, float* __restrict__ out0){
    int tid = threadIdx.x;
    int p = blockIdx.x*32 + (tid >> 3), dc = tid & 7;
    int j = idxb[p];
    short8_t zv = *(const short8_t*)(zpbf + (size_t)p*CODED + dc*8);
    short8_t cv = *(const short8_t*)(cbb  + (size_t)j*CODED + dc*8);
    float s = 0.f;
    #pragma unroll
    for (int i = 0; i < 8; i++){
        float d = bf2f((unsigned short)cv[i]) - bf2f((unsigned short)zv[i]);
        s += d*d;
    }
    #pragma unroll
    for (int o = 32; o; o >>= 1) s += __shfl_down(s, o);
    __shared__ float ps[4];
    int wave = tid >> 6, lane = tid & 63;
    if (lane == 0) ps[wave] = s;
    __syncthreads();
    if (tid == 0){
        float t = (ps[0] + ps[1] + ps[2] + ps[3]) * (1.25f/4194304.f);
        atomicAdd(out0, t);
    }
}

extern "C" void kernel_launch(void* const* d_in, const int* in_sizes, int n_in,
                              void* d_out, int out_size, void* d_ws, size_t ws_size,
                              hipStream_t stream) {
    (void)in_sizes; (void)n_in; (void)out_size; (void)ws_size;
    const float* z     = (const float*)d_in[0];
    const float* W_in  = (const float*)d_in[1];
    const float* b_in  = (const float*)d_in[2];
    const float* cb    = (const float*)d_in[3];
    const float* W_out = (const float*)d_in[4];
    const float* b_out = (const float*)d_in[5];
    float* outp = (float*)d_out;

    char* ws = (char*)d_ws;
    float*          Wt    = (float*)(ws);                       //    65536 B
    unsigned short* cbb   = (unsigned short*)(ws + 65536);      //   262144 B
    float*          cbias = (float*)(ws + 327680);              //     8192 B
    float*          pcb   = (float*)(ws + 335872);              //  2097152 B
    unsigned short* zpbf  = (unsigned short*)(ws + 2433024);    //  8388608 B
    int*            idxb  = (int*)(ws + 10821632);              //   262144 B  (total ~10.6 MB)

    hipMemsetAsync(d_out, 0, sizeof(float), stream);            // loss accumulator
    k_cbprep<<<NCODE/4, 256, 0, stream>>>(cb, cbb, cbias);
    k_wt    <<<CODED,   256, 0, stream>>>(W_in, Wt);
    k_projcb<<<NCODE/8, 256, 0, stream>>>(cb, W_out, b_out, pcb);
    k_projin<<<256,     256, 0, stream>>>(z, Wt, b_in, zpbf);
    k_argmin<<<256,     256, 0, stream>>>(zpbf, cbb, cbias, idxb);
    k_out   <<<2048,    256, 0, stream>>>(idxb, pcb, outp + 1);
    k_loss  <<<2048,    256, 0, stream>>>(zpbf, cbb, idxb, outp);
}

// Round 2
// 110.042 us; speedup vs baseline: 1.6711x; 1.6711x over previous
//
#include <hip/hip_runtime.h>
#include <hip/hip_bf16.h>

#define LATENT 256
#define CODED  64
#define NCODE  2048
#define NBATCH 64
#define HW     1024
#define NPIX   (NBATCH*HW)   // 65536
#define STEP   4             // jt tiles per LDS stage step in k_argmin

typedef __attribute__((ext_vector_type(8))) short  short8_t;   // bf16x8 MFMA frag
typedef __attribute__((ext_vector_type(4))) float  floatx4;

__device__ __forceinline__ unsigned int f2bf(float f){
    unsigned int x = __builtin_bit_cast(unsigned int, f);
    unsigned int r = (x + 0x7FFFu + ((x >> 16) & 1u)) >> 16;   // RNE
    return r & 0xFFFFu;
}
__device__ __forceinline__ float bf2f(unsigned short u){
    unsigned int x = ((unsigned int)u) << 16;
    return __builtin_bit_cast(float, x);
}
__device__ __forceinline__ short8_t as_s8(uint4 u){ return __builtin_bit_cast(short8_t, u); }
__device__ __forceinline__ floatx4  as_f4(uint4 u){ return __builtin_bit_cast(floatx4, u); }

// K0a: codebook -> bf16 row-major (for k_loss), cbias2[j] = 1.0 - 0.5*||cb_j||^2.
__global__ void k_cbprep(const float* __restrict__ cb, unsigned short* __restrict__ cbb,
                         float* __restrict__ cbias2){
    int wave = threadIdx.x >> 6, lane = threadIdx.x & 63;
    int j = blockIdx.x*4 + wave;
    float v = cb[j*CODED + lane];
    cbb[j*CODED + lane] = (unsigned short)f2bf(v);
    float s = v*v;
    #pragma unroll
    for (int o = 32; o; o >>= 1) s += __shfl_down(s, o);
    if (lane == 0) cbias2[j] = 1.0f - 0.5f*s;
}

// K0b: codebook -> MFMA-frag-ordered bf16. chunk=(jt*2+kk)*64+lane holds
// cb[jt*16+(lane&15)][kk*32+(lane>>4)*8 + 0..7]. grid 8 x 256
__global__ void k_cbfrag(const float* __restrict__ cb, uint4* __restrict__ cbf){
    int chunk = blockIdx.x*256 + threadIdx.x;          // 0..2047
    int lane = chunk & 63, kk = (chunk >> 6) & 1, jt = chunk >> 7;
    int row = jt*16 + (lane & 15), c0 = kk*32 + (lane >> 4)*8;
    const float* src = cb + row*CODED + c0;
    floatx4 f0 = *(const floatx4*)(src);
    floatx4 f1 = *(const floatx4*)(src + 4);
    uint4 o;
    o.x = f2bf(f0[0]) | (f2bf(f0[1]) << 16);
    o.y = f2bf(f0[2]) | (f2bf(f0[3]) << 16);
    o.z = f2bf(f1[0]) | (f2bf(f1[1]) << 16);
    o.w = f2bf(f1[2]) | (f2bf(f1[3]) << 16);
    cbf[chunk] = o;
}

// K0c: W_in -> MFMA-frag-ordered bf16. chunk=(t*8+kk)*64+lane holds
// W_in[t*16+(lane&15)][kk*32+(lane>>4)*8 + 0..7]. grid 8 x 256
__global__ void k_wfrag(const float* __restrict__ W_in, uint4* __restrict__ Wf){
    int chunk = blockIdx.x*256 + threadIdx.x;          // 0..2047
    int lane = chunk & 63, kk = (chunk >> 6) & 7, t = chunk >> 9;
    int row = t*16 + (lane & 15), c0 = kk*32 + (lane >> 4)*8;
    const float* src = W_in + row*LATENT + c0;
    floatx4 f0 = *(const floatx4*)(src);
    floatx4 f1 = *(const floatx4*)(src + 4);
    uint4 o;
    o.x = f2bf(f0[0]) | (f2bf(f0[1]) << 16);
    o.y = f2bf(f0[2]) | (f2bf(f0[3]) << 16);
    o.z = f2bf(f1[0]) | (f2bf(f1[1]) << 16);
    o.w = f2bf(f1[2]) | (f2bf(f1[3]) << 16);
    Wf[chunk] = o;
}

// K0d: pcb[j][n] = sum_d cb[j][d]*W_out[n][d] + b_out[n].  grid 256 x 256
__global__ void k_projcb(const float* __restrict__ cb, const float* __restrict__ W_out,
                         const float* __restrict__ b_out, float* __restrict__ pcb){
    __shared__ float cbl[8*CODED];
    int tid = threadIdx.x;
    int j0  = blockIdx.x*8;
    for (int k = tid; k < 8*CODED; k += 256) cbl[k] = cb[j0*CODED + k];
    __syncthreads();
    float wrow[CODED];
    #pragma unroll
    for (int k = 0; k < 16; k++)
        ((floatx4*)wrow)[k] = ((const floatx4*)(W_out + tid*CODED))[k];
    float bo = b_out[tid];
    for (int jj = 0; jj < 8; jj++){
        float acc = bo;
        #pragma unroll
        for (int d = 0; d < CODED; d++) acc += cbl[jj*CODED + d]*wrow[d];
        pcb[(j0+jj)*LATENT + tid] = acc;
    }
}

// K1: project_in via MFMA. A=W (M=64 d), B=64-px z^T tile (LDS), C-init=b_in.
// grid 1024 x 256 (block = 64 px), wave = 16 px.
__global__ __launch_bounds__(256) void k_projin(
        const float* __restrict__ z, const uint4* __restrict__ Wf,
        const float* __restrict__ b_in, unsigned short* __restrict__ zpbf){
    __shared__ unsigned int zT[64*130];     // [px][c2] packed 2xbf16, padded
    int tid = threadIdx.x;
    int b = blockIdx.x >> 4, p0 = (blockIdx.x & 15)*64;
    {   // stage z^T tile (bf16-packed)
        int p = tid & 63, cg = tid >> 6;    // cg in 0..3
        const float* zb = z + (size_t)b*(LATENT*HW) + p0 + p;
        #pragma unroll 4
        for (int i = 0; i < 32; i++){
            int c2 = i*4 + cg;              // 0..127
            float v0 = zb[(size_t)(2*c2)*HW];
            float v1 = zb[(size_t)(2*c2+1)*HW];
            zT[p*130 + c2] = f2bf(v0) | (f2bf(v1) << 16);
        }
    }
    __syncthreads();
    int wave = tid >> 6, lane = tid & 63;
    int col = lane & 15, g = lane >> 4;
    int pl = wave*16 + col;
    floatx4 acc[4];
    #pragma unroll
    for (int t = 0; t < 4; t++)
        acc[t] = *(const floatx4*)(b_in + t*16 + g*4);    // C-init = bias (row=d)
    const unsigned int* zrow = zT + pl*130;
    #pragma unroll
    for (int kk = 0; kk < 8; kk++){
        uint2 blo = *(const uint2*)(zrow + kk*16 + g*4);
        uint2 bhi = *(const uint2*)(zrow + kk*16 + g*4 + 2);
        uint4 bu; bu.x = blo.x; bu.y = blo.y; bu.z = bhi.x; bu.w = bhi.y;
        short8_t bf = as_s8(bu);
        #pragma unroll
        for (int t = 0; t < 4; t++){
            short8_t af = as_s8(Wf[(t*8 + kk)*64 + lane]);
            acc[t] = __builtin_amdgcn_mfma_f32_16x16x32_bf16(af, bf, acc[t], 0, 0, 0);
        }
    }
    size_t pg = (size_t)(b*HW + p0 + pl)*CODED;
    #pragma unroll
    for (int t = 0; t < 4; t++){
        uint2 st;
        st.x = f2bf(acc[t][0]) | (f2bf(acc[t][1]) << 16);
        st.y = f2bf(acc[t][2]) | (f2bf(acc[t][3]) << 16);
        *(uint2*)(zpbf + pg + t*16 + g*4) = st;         // d = t*16+g*4+r
    }
}

// K2: argmin via MFMA + packed-key argmax. Block = 4 waves x 32 px = 128 px,
// LDS-staged codebook tiles (double-buffered, STEP jt per stage). grid 512 x 256.
__global__ __launch_bounds__(256) void k_argmin(
        const unsigned short* __restrict__ zpbf, const uint4* __restrict__ cbf,
        const float* __restrict__ cbias2, int* __restrict__ idxb){
    __shared__ unsigned int biasl[NCODE];          // 8 KB (1.0-0.5||c||^2 as bits)
    __shared__ uint4 atile[2][STEP*2*64];          // 2 x 8 KB
    int tid = threadIdx.x, wave = tid >> 6, lane = tid & 63;
    int col = lane & 15, g = lane >> 4;
    {
        const unsigned int* cb32 = (const unsigned int*)cbias2;
        #pragma unroll
        for (int i = 0; i < 8; i++) biasl[i*256 + tid] = cb32[i*256 + tid];
    }
    int pixw = blockIdx.x*128 + wave*32;
    short8_t bfr[2][2];
    #pragma unroll
    for (int i = 0; i < 2; i++)
        #pragma unroll
        for (int kk = 0; kk < 2; kk++)
            bfr[i][kk] = *(const short8_t*)(zpbf + (size_t)(pixw + i*16 + col)*CODED + kk*32 + g*8);
    {   // stage step 0
        uint4 r0 = cbf[tid], r1 = cbf[256 + tid];
        atile[0][tid] = r0; atile[0][tid + 256] = r1;
    }
    __syncthreads();
    unsigned int jinv0 = 2047u - (unsigned)(g*4);
    unsigned int jinv1 = jinv0 - 1, jinv2 = jinv0 - 2, jinv3 = jinv0 - 3;
    unsigned int best0 = 0u, best1 = 0u;
    const unsigned int KMASK = 0xFFFFF800u;
    int cur = 0;
    for (int s = 0; s < 32; s++){
        uint4 r0, r1;
        if (s < 31){
            r0 = cbf[(s+1)*512 + tid];
            r1 = cbf[(s+1)*512 + 256 + tid];
        }
        #pragma unroll
        for (int jtl = 0; jtl < STEP; jtl++){
            int jt = s*STEP + jtl;
            const uint4* ab = &atile[cur][jtl*128];
            short8_t a0 = as_s8(ab[lane]);
            short8_t a1 = as_s8(ab[64 + lane]);
            floatx4 binit = as_f4(*(const uint4*)(biasl + jt*16 + g*4));
            {
                floatx4 d = binit;
                d = __builtin_amdgcn_mfma_f32_16x16x32_bf16(a0, bfr[0][0], d, 0, 0, 0);
                d = __builtin_amdgcn_mfma_f32_16x16x32_bf16(a1, bfr[0][1], d, 0, 0, 0);
                unsigned int u0 = __builtin_bit_cast(unsigned int, d[0]);
                unsigned int u1 = __builtin_bit_cast(unsigned int, d[1]);
                unsigned int u2 = __builtin_bit_cast(unsigned int, d[2]);
                unsigned int u3 = __builtin_bit_cast(unsigned int, d[3]);
                best0 = max(best0, (u0 & KMASK) | jinv0);
                best0 = max(best0, (u1 & KMASK) | jinv1);
                best0 = max(best0, (u2 & KMASK) | jinv2);
                best0 = max(best0, (u3 & KMASK) | jinv3);
            }
            {
                floatx4 d = binit;
                d = __builtin_amdgcn_mfma_f32_16x16x32_bf16(a0, bfr[1][0], d, 0, 0, 0);
                d = __builtin_amdgcn_mfma_f32_16x16x32_bf16(a1, bfr[1][1], d, 0, 0, 0);
                unsigned int u0 = __builtin_bit_cast(unsigned int, d[0]);
                unsigned int u1 = __builtin_bit_cast(unsigned int, d[1]);
                unsigned int u2 = __builtin_bit_cast(unsigned int, d[2]);
                unsigned int u3 = __builtin_bit_cast(unsigned int, d[3]);
                best1 = max(best1, (u0 & KMASK) | jinv0);
                best1 = max(best1, (u1 & KMASK) | jinv1);
                best1 = max(best1, (u2 & KMASK) | jinv2);
                best1 = max(best1, (u3 & KMASK) | jinv3);
            }
            jinv0 -= 16; jinv1 -= 16; jinv2 -= 16; jinv3 -= 16;
        }
        if (s < 31){
            atile[cur ^ 1][tid] = r0;
            atile[cur ^ 1][tid + 256] = r1;
        }
        __syncthreads();
        cur ^= 1;
    }
    // reduce across g groups (lanes xor 16, 32)
    #pragma unroll
    for (int off = 16; off < 64; off <<= 1){
        best0 = max(best0, (unsigned int)__shfl_xor((int)best0, off));
        best1 = max(best1, (unsigned int)__shfl_xor((int)best1, off));
    }
    if (lane < 16){
        idxb[pixw + lane]      = 2047 - (int)(best0 & 0x7FFu);
        idxb[pixw + 16 + lane] = 2047 - (int)(best1 & 0x7FFu);
    }
}

// K3: out[b][n][p] = pcb[idx[b,p]][n], via LDS transpose. grid 2048 x 256.
__global__ void k_out(const int* __restrict__ idxb, const float* __restrict__ pcb,
                      float* __restrict__ outp){
    __shared__ float lds[32][LATENT + 1];
    int tid = threadIdx.x;
    int b = blockIdx.x >> 5, pb = (blockIdx.x & 31)*32;
    for (int k = 0; k < 32; k++){
        int j = idxb[b*HW + pb + k];
        lds[k][tid] = pcb[(size_t)j*LATENT + tid];
    }
    __syncthreads();
    int p = tid & 31, ng = tid >> 5;
    for (int k = 0; k < 32; k++){
        int n = ng*32 + k;
        outp[((size_t)b*LATENT + n)*HW + pb + p] = lds[p][n];
    }
}

// K4: loss = 1.25 * mean((zq - zp)^2). grid 2048 x 256.
__global__ void k_loss(const unsigned short* __restrict__ zpbf,
                       const unsigned short* __restrict__ cbb,
                       const int* __restrict__ idxb, float* __restrict__ out0){
    int tid = threadIdx.x;
    int p = blockIdx.x*32 + (tid >> 3), dc = tid & 7;
    int j = idxb[p];
    short8_t zv = *(const short8_t*)(zpbf + (size_t)p*CODED + dc*8);
    short8_t cv = *(const short8_t*)(cbb  + (size_t)j*CODED + dc*8);
    float s = 0.f;
    #pragma unroll
    for (int i = 0; i < 8; i++){
        float d = bf2f((unsigned short)cv[i]) - bf2f((unsigned short)zv[i]);
        s += d*d;
    }
    #pragma unroll
    for (int o = 32; o; o >>= 1) s += __shfl_down(s, o);
    __shared__ float ps[4];
    int wave = tid >> 6, lane = tid & 63;
    if (lane == 0) ps[wave] = s;
    __syncthreads();
    if (tid == 0){
        float t = (ps[0] + ps[1] + ps[2] + ps[3]) * (1.25f/4194304.f);
        atomicAdd(out0, t);
    }
}

extern "C" void kernel_launch(void* const* d_in, const int* in_sizes, int n_in,
                              void* d_out, int out_size, void* d_ws, size_t ws_size,
                              hipStream_t stream) {
    (void)in_sizes; (void)n_in; (void)out_size; (void)ws_size;
    const float* z     = (const float*)d_in[0];
    const float* W_in  = (const float*)d_in[1];
    const float* b_in  = (const float*)d_in[2];
    const float* cb    = (const float*)d_in[3];
    const float* W_out = (const float*)d_in[4];
    const float* b_out = (const float*)d_in[5];
    float* outp = (float*)d_out;

    char* ws = (char*)d_ws;
    unsigned short* cbb    = (unsigned short*)(ws);              //   262144 B
    float*          cbias2 = (float*)(ws + 262144);              //     8192 B
    uint4*          cbf    = (uint4*)(ws + 270336);              //   262144 B
    uint4*          Wf     = (uint4*)(ws + 532480);              //    32768 B
    float*          pcb    = (float*)(ws + 565248);              //  2097152 B
    unsigned short* zpbf   = (unsigned short*)(ws + 2662400);    //  8388608 B
    int*            idxb   = (int*)(ws + 11051008);              //   262144 B (end ~11.31 MB)

    hipMemsetAsync(d_out, 0, sizeof(float), stream);             // loss accumulator
    k_cbprep<<<NCODE/4, 256, 0, stream>>>(cb, cbb, cbias2);
    k_cbfrag<<<8,       256, 0, stream>>>(cb, cbf);
    k_wfrag <<<8,       256, 0, stream>>>(W_in, Wf);
    k_projcb<<<NCODE/8, 256, 0, stream>>>(cb, W_out, b_out, pcb);
    k_projin<<<1024,    256, 0, stream>>>(z, Wf, b_in, zpbf);
    k_argmin<<<512,     256, 0, stream>>>(zpbf, cbf, cbias2, idxb);
    k_out   <<<2048,    256, 0, stream>>>(idxb, pcb, outp + 1);
    k_loss  <<<2048,    256, 0, stream>>>(zpbf, cbb, idxb, outp);
}

// Round 4
// 85.441 us; speedup vs baseline: 2.1523x; 1.2879x over previous
//
#include <hip/hip_runtime.h>
#include <hip/hip_bf16.h>

#define LATENT 256
#define CODED  64
#define NCODE  2048
#define HW     1024
#define STEP   4
#define KMASK  0xFFFFF800u

typedef __attribute__((ext_vector_type(8))) short  short8_t;   // bf16x8 MFMA frag
typedef __attribute__((ext_vector_type(4))) float  floatx4;

__device__ __forceinline__ unsigned int f2bf(float f){
    unsigned int x = __builtin_bit_cast(unsigned int, f);
    unsigned int r = (x + 0x7FFFu + ((x >> 16) & 1u)) >> 16;   // RNE
    return r & 0xFFFFu;
}
__device__ __forceinline__ unsigned int pk2bf(float lo, float hi){
    return f2bf(lo) | (f2bf(hi) << 16);
}
__device__ __forceinline__ short8_t as_s8(uint4 u){ return __builtin_bit_cast(short8_t, u); }
__device__ __forceinline__ float    as_f (unsigned int u){ return __builtin_bit_cast(float, u); }
__device__ __forceinline__ unsigned int as_u(float f){ return __builtin_bit_cast(unsigned int, f); }

// K0: all precomputes in one kernel. grid 328 x 256:
//   bid   0..63 : cbf  (codebook -> MFMA A-frag order, 16384 uint4)  [R2 bug fixed: full jt<128]
//   bid  64..71 : Wf   (W_in -> MFMA A-frag order, 2048 uint4); bid64/tid0 zeroes loss accum
//   bid 72..327 : pcb[j][n] = cb[j]·W_out[n] + b_out[n]
__global__ __launch_bounds__(256) void k_prep(const float* __restrict__ cb,
        const float* __restrict__ W_in, const float* __restrict__ W_out,
        const float* __restrict__ b_out, uint4* __restrict__ cbf,
        uint4* __restrict__ Wf, float* __restrict__ pcb, float* __restrict__ out0){
    __shared__ float cbl[8*CODED];
    int bid = blockIdx.x, tid = threadIdx.x;
    if (bid < 64){
        int chunk = bid*256 + tid;                 // 0..16383
        int lane = chunk & 63, kk = (chunk >> 6) & 1, jt = chunk >> 7;
        int row = jt*16 + (lane & 15), c0 = kk*32 + (lane >> 4)*8;
        const float* src = cb + row*CODED + c0;
        floatx4 f0 = *(const floatx4*)(src);
        floatx4 f1 = *(const floatx4*)(src + 4);
        uint4 o;
        o.x = pk2bf(f0[0], f0[1]); o.y = pk2bf(f0[2], f0[3]);
        o.z = pk2bf(f1[0], f1[1]); o.w = pk2bf(f1[2], f1[3]);
        cbf[chunk] = o;
    } else if (bid < 72){
        if (bid == 64 && tid == 0) out0[0] = 0.f;
        int chunk = (bid - 64)*256 + tid;          // 0..2047
        int lane = chunk & 63, kk = (chunk >> 6) & 7, t = chunk >> 9;
        int row = t*16 + (lane & 15), c0 = kk*32 + (lane >> 4)*8;
        const float* src = W_in + row*LATENT + c0;
        floatx4 f0 = *(const floatx4*)(src);
        floatx4 f1 = *(const floatx4*)(src + 4);
        uint4 o;
        o.x = pk2bf(f0[0], f0[1]); o.y = pk2bf(f0[2], f0[3]);
        o.z = pk2bf(f1[0], f1[1]); o.w = pk2bf(f1[2], f1[3]);
        Wf[chunk] = o;
    } else {
        int j0 = (bid - 72)*8;
        for (int k = tid; k < 8*CODED; k += 256) cbl[k] = cb[j0*CODED + k];
        __syncthreads();
        float wrow[CODED];
        #pragma unroll
        for (int k = 0; k < 16; k++)
            ((floatx4*)wrow)[k] = ((const floatx4*)(W_out + tid*CODED))[k];
        float bo = b_out[tid];
        for (int jj = 0; jj < 8; jj++){
            float acc = bo;
            #pragma unroll
            for (int d = 0; d < CODED; d++) acc += cbl[jj*CODED + d]*wrow[d];
            pcb[(j0+jj)*LATENT + tid] = acc;
        }
    }
}

// K1: fused project_in + argmin + loss. grid 512 x 256 (128 px/block, 4 waves,
// 2 ptiles of 16 px per wave). Phase A: zp via MFMA (A=Wf, B=z direct-global),
// bf16 round-trip through XOR-swizzled zpl (per-wave private). Phase B: argmin
// over 2048 codes, A-tiles double-buffered in LDS, packed-key fmax argmax
// (bias term ||c||^2/2 ~ 4e-6 dropped: below the 2^-12 key quantization).
// Loss folded in: loss_p = ||zp||^2 + 2 - 2*value(best & KMASK).
__global__ __launch_bounds__(256) void k_main(const float* __restrict__ z,
        const uint4* __restrict__ Wf, const float* __restrict__ b_in,
        const uint4* __restrict__ cbf, int* __restrict__ idxb,
        float* __restrict__ out0){
    __shared__ uint4 atile[2][512];                       // 16 KB
    __shared__ __align__(16) unsigned int zpl[4096];      // 16 KB, per-wave slices
    __shared__ float ps[4];
    int tid = threadIdx.x, wave = tid >> 6, lane = tid & 63;
    int col = lane & 15, g = lane >> 4;
    int b  = blockIdx.x >> 3;
    int p0 = (blockIdx.x & 7)*128 + wave*32;              // wave's first px
    const unsigned int swz = (unsigned)((col & 7) << 2);  // 4-word-aligned XOR

    // ---------- Phase A: project_in for 2 ptiles ----------
    float szp[2];
    #pragma unroll
    for (int pt = 0; pt < 2; pt++){
        floatx4 acc[4];
        #pragma unroll
        for (int t = 0; t < 4; t++) acc[t] = *(const floatx4*)(b_in + t*16 + g*4);
        const float* zp0 = z + ((size_t)b*LATENT + g*8)*HW + p0 + pt*16 + col;
        #pragma unroll 2
        for (int kk = 0; kk < 8; kk++){
            const float* zr = zp0 + (size_t)kk*32*HW;
            float f[8];
            #pragma unroll
            for (int i = 0; i < 8; i++) f[i] = zr[(size_t)i*HW];
            uint4 bu;
            bu.x = pk2bf(f[0], f[1]); bu.y = pk2bf(f[2], f[3]);
            bu.z = pk2bf(f[4], f[5]); bu.w = pk2bf(f[6], f[7]);
            short8_t bf = as_s8(bu);
            #pragma unroll
            for (int t = 0; t < 4; t++){
                short8_t af = as_s8(Wf[(t*8 + kk)*64 + lane]);
                acc[t] = __builtin_amdgcn_mfma_f32_16x16x32_bf16(af, bf, acc[t], 0, 0, 0);
            }
        }
        float s = 0.f;
        #pragma unroll
        for (int t = 0; t < 4; t++)
            #pragma unroll
            for (int r = 0; r < 4; r++) s += acc[t][r]*acc[t][r];
        szp[pt] = s;
        unsigned int* zb = zpl + ((wave*2 + pt)*16 + col)*32;
        #pragma unroll
        for (int t = 0; t < 4; t++){
            uint2 w;
            w.x = pk2bf(acc[t][0], acc[t][1]);
            w.y = pk2bf(acc[t][2], acc[t][3]);
            *(uint2*)(zb + (((unsigned)(t*8 + g*2)) ^ swz)) = w;   // d = t*16+g*4+r
        }
    }
    // B-frags: lane (col,g) needs zp[px=col][kk*32+g*8 .. +7]  (same-wave LDS RAW)
    short8_t bfr[2][2];
    #pragma unroll
    for (int pt = 0; pt < 2; pt++){
        const unsigned int* zb = zpl + ((wave*2 + pt)*16 + col)*32;
        #pragma unroll
        for (int kk = 0; kk < 2; kk++)
            bfr[pt][kk] = as_s8(*(const uint4*)(zb + (((unsigned)(kk*16 + g*4)) ^ swz)));
    }

    // ---------- Phase B: argmin over codebook ----------
    {   uint4 r0 = cbf[tid], r1 = cbf[256 + tid];
        atile[0][tid] = r0; atile[0][tid + 256] = r1; }
    __syncthreads();
    unsigned int jinv0 = 2047u - (unsigned)(g*4);
    unsigned int jinv1 = jinv0 - 1, jinv2 = jinv0 - 2, jinv3 = jinv0 - 3;
    float best0 = 0.f, best1 = 0.f;
    int cur = 0;
    for (int s = 0; s < 32; s++){
        uint4 r0, r1;
        if (s < 31){
            r0 = cbf[(s+1)*512 + tid];
            r1 = cbf[(s+1)*512 + 256 + tid];
        }
        #pragma unroll
        for (int jtl = 0; jtl < STEP; jtl++){
            const uint4* ab = &atile[cur][jtl*128];
            short8_t a0 = as_s8(ab[lane]);
            short8_t a1 = as_s8(ab[64 + lane]);
            floatx4 d0 = {1.f, 1.f, 1.f, 1.f};
            d0 = __builtin_amdgcn_mfma_f32_16x16x32_bf16(a0, bfr[0][0], d0, 0, 0, 0);
            d0 = __builtin_amdgcn_mfma_f32_16x16x32_bf16(a1, bfr[0][1], d0, 0, 0, 0);
            best0 = fmaxf(fmaxf(best0, as_f((as_u(d0[0]) & KMASK) | jinv0)),
                                       as_f((as_u(d0[1]) & KMASK) | jinv1));
            best0 = fmaxf(fmaxf(best0, as_f((as_u(d0[2]) & KMASK) | jinv2)),
                                       as_f((as_u(d0[3]) & KMASK) | jinv3));
            floatx4 d1 = {1.f, 1.f, 1.f, 1.f};
            d1 = __builtin_amdgcn_mfma_f32_16x16x32_bf16(a0, bfr[1][0], d1, 0, 0, 0);
            d1 = __builtin_amdgcn_mfma_f32_16x16x32_bf16(a1, bfr[1][1], d1, 0, 0, 0);
            best1 = fmaxf(fmaxf(best1, as_f((as_u(d1[0]) & KMASK) | jinv0)),
                                       as_f((as_u(d1[1]) & KMASK) | jinv1));
            best1 = fmaxf(fmaxf(best1, as_f((as_u(d1[2]) & KMASK) | jinv2)),
                                       as_f((as_u(d1[3]) & KMASK) | jinv3));
            jinv0 -= 16; jinv1 -= 16; jinv2 -= 16; jinv3 -= 16;
        }
        if (s < 31){
            atile[cur ^ 1][tid] = r0;
            atile[cur ^ 1][tid + 256] = r1;
        }
        __syncthreads();
        cur ^= 1;
    }

    // ---------- Epilogue: reduce over g-groups, write idx, accumulate loss ----------
    #pragma unroll
    for (int off = 16; off < 64; off <<= 1){
        best0 = fmaxf(best0, __shfl_xor(best0, off));
        best1 = fmaxf(best1, __shfl_xor(best1, off));
        szp[0] += __shfl_xor(szp[0], off);
        szp[1] += __shfl_xor(szp[1], off);
    }
    if (lane < 16){
        idxb[b*HW + p0 + lane]      = 2047 - (int)(as_u(best0) & 0x7FFu);
        idxb[b*HW + p0 + 16 + lane] = 2047 - (int)(as_u(best1) & 0x7FFu);
    }
    float lossp = (szp[0] + 2.f - 2.f*as_f(as_u(best0) & KMASK))
                + (szp[1] + 2.f - 2.f*as_f(as_u(best1) & KMASK));
    #pragma unroll
    for (int o = 32; o; o >>= 1) lossp += __shfl_down(lossp, o);
    if (lane == 0) ps[wave] = lossp;
    __syncthreads();
    if (tid == 0)
        atomicAdd(out0, (ps[0] + ps[1] + ps[2] + ps[3]) * (1.25f/(4194304.f*4.f)));
}

// K2: out[b][n][p] = pcb[idx[b,p]][n], via LDS transpose. grid 2048 x 256.
__global__ void k_out(const int* __restrict__ idxb, const float* __restrict__ pcb,
                      float* __restrict__ outp){
    __shared__ float lds[32][LATENT + 1];
    int tid = threadIdx.x;
    int b = blockIdx.x >> 5, pb = (blockIdx.x & 31)*32;
    for (int k = 0; k < 32; k++){
        int j = idxb[b*HW + pb + k];
        lds[k][tid] = pcb[(size_t)j*LATENT + tid];
    }
    __syncthreads();
    int p = tid & 31, ng = tid >> 5;
    for (int k = 0; k < 32; k++){
        int n = ng*32 + k;
        outp[((size_t)b*LATENT + n)*HW + pb + p] = lds[p][n];
    }
}

extern "C" void kernel_launch(void* const* d_in, const int* in_sizes, int n_in,
                              void* d_out, int out_size, void* d_ws, size_t ws_size,
                              hipStream_t stream) {
    (void)in_sizes; (void)n_in; (void)out_size; (void)ws_size;
    const float* z     = (const float*)d_in[0];
    const float* W_in  = (const float*)d_in[1];
    const float* b_in  = (const float*)d_in[2];
    const float* cb    = (const float*)d_in[3];
    const float* W_out = (const float*)d_in[4];
    const float* b_out = (const float*)d_in[5];
    float* outp = (float*)d_out;

    char* ws = (char*)d_ws;
    uint4* cbf  = (uint4*)(ws);              //  262144 B (16384 uint4)
    uint4* Wf   = (uint4*)(ws + 262144);     //   32768 B ( 2048 uint4)
    float* pcb  = (float*)(ws + 294912);     // 2097152 B
    int*   idxb = (int*)(ws + 2392064);      //  262144 B  (end ~2.65 MB)

    k_prep<<<328,  256, 0, stream>>>(cb, W_in, W_out, b_out, cbf, Wf, pcb, outp);
    k_main<<<512,  256, 0, stream>>>(z, Wf, b_in, cbf, idxb, outp);
    k_out <<<2048, 256, 0, stream>>>(idxb, pcb, outp + 1);
}